// Round 10
// baseline (255.499 us; speedup 1.0000x reference)
//
#include <hip/hip_runtime.h>
#include <hip/hip_bf16.h>
#include <math.h>

#define NN 100000
#define NE 625000
#define DIN 128
#define DH 256
#define NROWS 100096                      // 782 tiles * 128 rows
#define NTILES 782

#define SCAN_BS 1024
#define NB ((NN + SCAN_BS - 1) / SCAN_BS) // 98 scan blocks

#define HS_STRIDE 264                     // bf16 elems; 528 B rows, 16B-aligned

// prep kernel block ranges
#define XCAST_BLOCKS 12500                // NN*32 / 256 exactly
#define HIST_BLOCKS  2442
#define PACKW_BLOCKS 32
#define PACKH_BLOCKS 2
#define PREP_BLOCKS  (XCAST_BLOCKS + HIST_BLOCKS + PACKW_BLOCKS + PACKH_BLOCKS)

typedef __attribute__((ext_vector_type(8))) short bf16x8;
typedef __attribute__((ext_vector_type(4))) float f32x4;

__device__ __forceinline__ unsigned short f2bf(float f) {
    unsigned u = __builtin_bit_cast(unsigned, f);
    u += 0x7fffu + ((u >> 16) & 1u);      // RNE
    return (unsigned short)(u >> 16);
}
__device__ __forceinline__ float bflo(unsigned u) {
    return __builtin_bit_cast(float, u << 16);
}
__device__ __forceinline__ float bfhi(unsigned u) {
    return __builtin_bit_cast(float, u & 0xffff0000u);
}

// ---------------------------------------------------------------------------
// prep: fused xcast | hist | pack_w (HALF-contiguous) | pack_heads
// ---------------------------------------------------------------------------
__global__ __launch_bounds__(256)
void prep(const float* __restrict__ x, const int* __restrict__ ei,
          const float* __restrict__ w_l, const float* __restrict__ w_r,
          const float* __restrict__ w_p, const float* __restrict__ w_s,
          const float* __restrict__ b_p, const float* __restrict__ b_s,
          unsigned short* __restrict__ A, unsigned short* __restrict__ Bp,
          unsigned short* __restrict__ whp, float* __restrict__ bhc,
          int* __restrict__ deg) {
    const int b = blockIdx.x;
    const int t = threadIdx.x;

    if (b < XCAST_BLOCKS) {
        int idx = b * 256 + t;
        int n = idx >> 5;
        int j4 = (idx & 31) * 4;
        float4 v = *reinterpret_cast<const float4*>(x + (size_t)n * DIN + j4);
        ushort4 o = { f2bf(v.x), f2bf(v.y), f2bf(v.z), f2bf(v.w) };
        *reinterpret_cast<ushort4*>(A + (size_t)n * 256 + 128 + j4) = o;
    } else if (b < XCAST_BLOCKS + HIST_BLOCKS) {
        int e = (b - XCAST_BLOCKS) * 256 + t;
        if (e < NE) atomicAdd(&deg[ei[NE + e]], 1);
    } else if (b < XCAST_BLOCKS + HIST_BLOCKS + PACKW_BLOCKS) {
        // pack_w, col-half-contiguous:
        // Bp[(((h*8+kt)*8+c8)*64+L)*8+j] =
        //   bf16(w_cat[kt*32+(L>>4)*8+j][(h*8+c8)*16+(L&15)])
        int tid = (b - XCAST_BLOCKS - HIST_BLOCKS) * 256 + t;   // 8192
        int h = tid >> 12;
        int kt = (tid >> 9) & 7;
        int c8 = (tid >> 6) & 7;
        int L = tid & 63;
        int k0 = kt * 32 + (L >> 4) * 8;
        int c = (h * 8 + c8) * 16 + (L & 15);
        unsigned short v[8];
#pragma unroll
        for (int j = 0; j < 8; ++j) {
            int k = k0 + j;
            float w = (k < 128) ? w_l[k * 256 + c] : w_r[(k - 128) * 256 + c];
            v[j] = f2bf(w);
        }
        *reinterpret_cast<bf16x8*>(Bp + (size_t)tid * 8) =
            *reinterpret_cast<const bf16x8*>(v);
    } else {
        int tid = (b - XCAST_BLOCKS - HIST_BLOCKS - PACKW_BLOCKS) * 256 + t; // 512
        int kt = tid >> 6;
        int L = tid & 63;
        int k0 = kt * 32 + (L >> 4) * 8;
        int c = L & 15;
        unsigned short v[8];
#pragma unroll
        for (int j = 0; j < 8; ++j) {
            int k = k0 + j;
            float w = (c < 7) ? w_p[k * 7 + c] : (c < 13 ? w_s[k * 6 + (c - 7)] : 0.f);
            v[j] = f2bf(w);
        }
        *reinterpret_cast<bf16x8*>(whp + (size_t)tid * 8) =
            *reinterpret_cast<const bf16x8*>(v);
        if (tid < 16)
            bhc[tid] = (tid < 7) ? b_p[tid] : (tid < 13 ? b_s[tid - 7] : 0.f);
    }
}

// ---------------------------------------------------------------------------
// CSR scans
// ---------------------------------------------------------------------------
__global__ __launch_bounds__(256)
void sage_scan1(const int* __restrict__ deg, int* __restrict__ cursor,
                int* __restrict__ bsums) {
    __shared__ int ss[256];
    const int t = threadIdx.x;
    const int base = blockIdx.x * SCAN_BS + t * 4;
    int v[4];
#pragma unroll
    for (int j = 0; j < 4; ++j) v[j] = (base + j < NN) ? deg[base + j] : 0;
    int tsum = v[0] + v[1] + v[2] + v[3];
    ss[t] = tsum;
    __syncthreads();
    for (int o = 1; o < 256; o <<= 1) {
        int u = (t >= o) ? ss[t - o] : 0;
        __syncthreads();
        ss[t] += u;
        __syncthreads();
    }
    int run = ss[t] - tsum;
#pragma unroll
    for (int j = 0; j < 4; ++j) {
        if (base + j < NN) cursor[base + j] = run;
        run += v[j];
    }
    if (t == 255) bsums[blockIdx.x] = ss[255];
}

__global__ __launch_bounds__(128)
void sage_scan2(int* __restrict__ bsums) {
    __shared__ int ss[128];
    const int t = threadIdx.x;
    int v = (t < NB) ? bsums[t] : 0;
    ss[t] = v;
    __syncthreads();
    for (int o = 1; o < 128; o <<= 1) {
        int u = (t >= o) ? ss[t - o] : 0;
        __syncthreads();
        ss[t] += u;
        __syncthreads();
    }
    if (t < NB) bsums[t] = ss[t] - v;
}

// ---------------------------------------------------------------------------
// CSR fill: pos = bsums[dst>>10] + local cursor++
// ---------------------------------------------------------------------------
__global__ __launch_bounds__(256)
void sage_fill(const int* __restrict__ ei, int* __restrict__ cursor,
               const int* __restrict__ bsums, int* __restrict__ elist) {
    int e = blockIdx.x * 256 + threadIdx.x;
    if (e >= NE) return;
    int dst = ei[NE + e];
    int p = bsums[dst >> 10] + atomicAdd(&cursor[dst], 1);
    elist[p] = ei[e];
}

// ---------------------------------------------------------------------------
// Fused gather-mean + MFMA GEMM + heads + log_softmax.
// R9 structure, but B staged in two 64 KB col-halves so LDS = 76288 B ->
// 2 blocks/CU (16 waves/CU). No min-waves bound: keep the no-spill regime.
// ---------------------------------------------------------------------------
__global__ __launch_bounds__(512, 1)
void sage_gemm_fused(const unsigned short* __restrict__ A,
                     const unsigned short* __restrict__ Bp,
                     const float* __restrict__ b_l,
                     const unsigned short* __restrict__ whp,
                     const float* __restrict__ bhc,
                     const int* __restrict__ elist,
                     const int* __restrict__ cursor,
                     const int* __restrict__ bsums,
                     const int* __restrict__ deg,
                     float* __restrict__ out) {
    __shared__ __align__(16) unsigned char smem[76288];
    unsigned short* Bs = (unsigned short*)smem;          // 64 KB B col-half
    unsigned short* hs = (unsigned short*)smem;          // [128][264] bf16 (alias)
    float* o13 = (float*)(smem + 67584);                 // [128][17]

    const int t = threadIdx.x;
    const int wave = t >> 6;
    const int L = t & 63;
    const int q = L >> 4;
    const int m15 = L & 15;
    const int node0 = blockIdx.x * 128;
    const int n = node0 + wave * 16 + m15;   // this lane's A-frag row

    // ---- stage B half0 (cols 0..127): 8 rounds x 512 thr x 16 B ----
    {
        const uint4* gsrc = reinterpret_cast<const uint4*>(Bp);
        uint4* ldst = reinterpret_cast<uint4*>(Bs);
#pragma unroll
        for (int r = 0; r < 8; ++r)
            ldst[r * 512 + t] = gsrc[r * 512 + t];
    }

    // ---- x-half A fragments (kt = 4..7): own row, direct loads ----
    bf16x8 afrag[8];
    {
        const unsigned short* arow = A + (size_t)n * 256;
#pragma unroll
        for (int kt = 4; kt < 8; ++kt)
            afrag[kt] = *reinterpret_cast<const bf16x8*>(arow + kt * 32 + q * 8);
    }

    // ---- gather-mean for kt = 0..3, unrolled x2 over neighbors ----
    {
        float macc[32];
#pragma unroll
        for (int j = 0; j < 32; ++j) macc[j] = 0.f;
        int d = 0, start = 0;
        if (n < NN) {
            d = deg[n];
            start = bsums[n >> 10] + cursor[n] - d;  // cursor = local_pfx + deg
        }
        int srcA = (d > 0) ? elist[start] : 0;
        int srcB = (d > 1) ? elist[start + 1] : 0;
        int i = 0;
        for (; i + 1 < d; i += 2) {
            const int sA = srcA, sB = srcB;
            if (i + 2 < d) srcA = elist[start + i + 2];
            if (i + 3 < d) srcB = elist[start + i + 3];
            const unsigned short* xa = A + (size_t)sA * 256 + 128 + q * 8;
            const unsigned short* xb = A + (size_t)sB * 256 + 128 + q * 8;
            const uint4 a0 = *reinterpret_cast<const uint4*>(xa);
            const uint4 a1 = *reinterpret_cast<const uint4*>(xa + 32);
            const uint4 a2 = *reinterpret_cast<const uint4*>(xa + 64);
            const uint4 a3 = *reinterpret_cast<const uint4*>(xa + 96);
            const uint4 b0 = *reinterpret_cast<const uint4*>(xb);
            const uint4 b1 = *reinterpret_cast<const uint4*>(xb + 32);
            const uint4 b2 = *reinterpret_cast<const uint4*>(xb + 64);
            const uint4 b3 = *reinterpret_cast<const uint4*>(xb + 96);
            macc[0]  += bflo(a0.x) + bflo(b0.x); macc[1]  += bfhi(a0.x) + bfhi(b0.x);
            macc[2]  += bflo(a0.y) + bflo(b0.y); macc[3]  += bfhi(a0.y) + bfhi(b0.y);
            macc[4]  += bflo(a0.z) + bflo(b0.z); macc[5]  += bfhi(a0.z) + bfhi(b0.z);
            macc[6]  += bflo(a0.w) + bflo(b0.w); macc[7]  += bfhi(a0.w) + bfhi(b0.w);
            macc[8]  += bflo(a1.x) + bflo(b1.x); macc[9]  += bfhi(a1.x) + bfhi(b1.x);
            macc[10] += bflo(a1.y) + bflo(b1.y); macc[11] += bfhi(a1.y) + bfhi(b1.y);
            macc[12] += bflo(a1.z) + bflo(b1.z); macc[13] += bfhi(a1.z) + bfhi(b1.z);
            macc[14] += bflo(a1.w) + bflo(b1.w); macc[15] += bfhi(a1.w) + bfhi(b1.w);
            macc[16] += bflo(a2.x) + bflo(b2.x); macc[17] += bfhi(a2.x) + bfhi(b2.x);
            macc[18] += bflo(a2.y) + bflo(b2.y); macc[19] += bfhi(a2.y) + bfhi(b2.y);
            macc[20] += bflo(a2.z) + bflo(b2.z); macc[21] += bfhi(a2.z) + bfhi(b2.z);
            macc[22] += bflo(a2.w) + bflo(b2.w); macc[23] += bfhi(a2.w) + bfhi(b2.w);
            macc[24] += bflo(a3.x) + bflo(b3.x); macc[25] += bfhi(a3.x) + bfhi(b3.x);
            macc[26] += bflo(a3.y) + bflo(b3.y); macc[27] += bfhi(a3.y) + bfhi(b3.y);
            macc[28] += bflo(a3.z) + bflo(b3.z); macc[29] += bfhi(a3.z) + bfhi(b3.z);
            macc[30] += bflo(a3.w) + bflo(b3.w); macc[31] += bfhi(a3.w) + bfhi(b3.w);
        }
        if (i < d) {
            const unsigned short* xa = A + (size_t)srcA * 256 + 128 + q * 8;
            const uint4 a0 = *reinterpret_cast<const uint4*>(xa);
            const uint4 a1 = *reinterpret_cast<const uint4*>(xa + 32);
            const uint4 a2 = *reinterpret_cast<const uint4*>(xa + 64);
            const uint4 a3 = *reinterpret_cast<const uint4*>(xa + 96);
            macc[0]  += bflo(a0.x); macc[1]  += bfhi(a0.x);
            macc[2]  += bflo(a0.y); macc[3]  += bfhi(a0.y);
            macc[4]  += bflo(a0.z); macc[5]  += bfhi(a0.z);
            macc[6]  += bflo(a0.w); macc[7]  += bfhi(a0.w);
            macc[8]  += bflo(a1.x); macc[9]  += bfhi(a1.x);
            macc[10] += bflo(a1.y); macc[11] += bfhi(a1.y);
            macc[12] += bflo(a1.z); macc[13] += bfhi(a1.z);
            macc[14] += bflo(a1.w); macc[15] += bfhi(a1.w);
            macc[16] += bflo(a2.x); macc[17] += bfhi(a2.x);
            macc[18] += bflo(a2.y); macc[19] += bfhi(a2.y);
            macc[20] += bflo(a2.z); macc[21] += bfhi(a2.z);
            macc[22] += bflo(a2.w); macc[23] += bfhi(a2.w);
            macc[24] += bflo(a3.x); macc[25] += bfhi(a3.x);
            macc[26] += bflo(a3.y); macc[27] += bfhi(a3.y);
            macc[28] += bflo(a3.z); macc[29] += bfhi(a3.z);
            macc[30] += bflo(a3.w); macc[31] += bfhi(a3.w);
        }
        const float invd = (d > 0) ? 1.f / (float)d : 0.f;
#pragma unroll
        for (int kt = 0; kt < 4; ++kt) {
            unsigned short vv[8];
#pragma unroll
            for (int j = 0; j < 8; ++j) vv[j] = f2bf(macc[kt * 8 + j] * invd);
            afrag[kt] = *reinterpret_cast<const bf16x8*>(vv);
        }
    }

    f32x4 acc[16];
#pragma unroll
    for (int ct = 0; ct < 16; ++ct) acc[ct] = (f32x4){0.f, 0.f, 0.f, 0.f};

    __syncthreads();   // B half0 staged (gather register-private)

#pragma unroll
    for (int kt = 0; kt < 8; ++kt)
#pragma unroll
        for (int c8 = 0; c8 < 8; ++c8) {
            bf16x8 b = *reinterpret_cast<const bf16x8*>(
                Bs + ((size_t)(kt * 8 + c8) * 64 + L) * 8);
            acc[c8] = __builtin_amdgcn_mfma_f32_16x16x32_bf16(afrag[kt], b, acc[c8], 0, 0, 0);
        }
    __syncthreads();   // done reading half0

    // ---- stage B half1 (cols 128..255) ----
    {
        const uint4* gsrc = reinterpret_cast<const uint4*>(Bp) + 4096;
        uint4* ldst = reinterpret_cast<uint4*>(Bs);
#pragma unroll
        for (int r = 0; r < 8; ++r)
            ldst[r * 512 + t] = gsrc[r * 512 + t];
    }
    __syncthreads();

#pragma unroll
    for (int kt = 0; kt < 8; ++kt)
#pragma unroll
        for (int c8 = 0; c8 < 8; ++c8) {
            bf16x8 b = *reinterpret_cast<const bf16x8*>(
                Bs + ((size_t)(kt * 8 + c8) * 64 + L) * 8);
            acc[8 + c8] = __builtin_amdgcn_mfma_f32_16x16x32_bf16(afrag[kt], b, acc[8 + c8], 0, 0, 0);
        }
    __syncthreads();   // done reading half1; reuse region as hs

    // ---- epilogue: bias + relu -> hs bf16 (stride 264) ----
#pragma unroll
    for (int ct = 0; ct < 16; ++ct) {
        const int c = ct * 16 + m15;
        const float blv = b_l[c];
        const int r0 = wave * 16 + q * 4;
#pragma unroll
        for (int r = 0; r < 4; ++r)
            hs[(r0 + r) * HS_STRIDE + c] = f2bf(fmaxf(acc[ct][r] + blv, 0.f));
    }
    __syncthreads();

    // ---- heads via MFMA: wave's 16 rows x 16 (13 used) cols, K=256 ----
    {
        f32x4 acch = (f32x4){0.f, 0.f, 0.f, 0.f};
        const unsigned short* hrow = hs + (size_t)(wave * 16 + m15) * HS_STRIDE;
#pragma unroll
        for (int kt = 0; kt < 8; ++kt) {
            bf16x8 ah = *reinterpret_cast<const bf16x8*>(hrow + kt * 32 + q * 8);
            bf16x8 bh = *reinterpret_cast<const bf16x8*>(whp + ((size_t)(kt * 64 + L)) * 8);
            acch = __builtin_amdgcn_mfma_f32_16x16x32_bf16(ah, bh, acch, 0, 0, 0);
        }
        if (m15 < 13) {
            const float bh = bhc[m15];
#pragma unroll
            for (int r = 0; r < 4; ++r)
                o13[(wave * 16 + q * 4 + r) * 17 + m15] = acch[r] + bh;
        }
    }
    __syncthreads();

    // ---- log_softmax + write ----
    if (t < 128) {
        const int gnode = node0 + t;
        if (gnode < NN) {
            float v[7], mx = -1e30f;
#pragma unroll
            for (int j = 0; j < 7; ++j) { v[j] = o13[t * 17 + j]; mx = fmaxf(mx, v[j]); }
            float sum = 0.f;
#pragma unroll
            for (int j = 0; j < 7; ++j) sum += expf(v[j] - mx);
            const float lse = mx + logf(sum);
#pragma unroll
            for (int j = 0; j < 7; ++j) out[(size_t)gnode * 7 + j] = v[j] - lse;

            float u[6], mx2 = -1e30f;
#pragma unroll
            for (int j = 0; j < 6; ++j) { u[j] = o13[t * 17 + 7 + j]; mx2 = fmaxf(mx2, u[j]); }
            float sum2 = 0.f;
#pragma unroll
            for (int j = 0; j < 6; ++j) sum2 += expf(u[j] - mx2);
            const float lse2 = mx2 + logf(sum2);
#pragma unroll
            for (int j = 0; j < 6; ++j) out[(size_t)NN * 7 + (size_t)gnode * 6 + j] = u[j] - lse2;
        }
    }
}

extern "C" void kernel_launch(void* const* d_in, const int* in_sizes, int n_in,
                              void* d_out, int out_size, void* d_ws, size_t ws_size,
                              hipStream_t stream) {
    const float* x   = (const float*)d_in[0];
    const int*   ei  = (const int*)d_in[1];
    const float* w_l = (const float*)d_in[2];
    const float* b_l = (const float*)d_in[3];
    const float* w_r = (const float*)d_in[4];
    const float* w_p = (const float*)d_in[5];
    const float* b_p = (const float*)d_in[6];
    const float* w_s = (const float*)d_in[7];
    const float* b_s = (const float*)d_in[8];
    float* out = (float*)d_out;

    // workspace layout (~54.7 MB)
    unsigned short* A   = (unsigned short*)d_ws;     // [NROWS][256] bf16: [mean|x]
    unsigned short* Bp  = A + (size_t)NROWS * 256;   // 65536 bf16 (half-contiguous)
    unsigned short* whp = Bp + 65536;                // 4096 bf16 head B-frags
    float* bhc  = (float*)(whp + 4096);              // [16] head biases
    int* deg    = (int*)(bhc + 16);                  // NN
    int* cursor = deg + NN;                          // NN (local prefix)
    int* bsums  = cursor + NN;                       // 128
    int* elist  = bsums + 128;                       // NE

    hipMemsetAsync(deg, 0, NN * sizeof(int), stream);

    prep<<<PREP_BLOCKS, 256, 0, stream>>>(x, ei, w_l, w_r, w_p, w_s, b_p, b_s,
                                          A, Bp, whp, bhc, deg);
    sage_scan1<<<NB, 256, 0, stream>>>(deg, cursor, bsums);
    sage_scan2<<<1, 128, 0, stream>>>(bsums);
    sage_fill<<<(NE + 255) / 256, 256, 0, stream>>>(ei, cursor, bsums, elist);

    sage_gemm_fused<<<NTILES, 512, 0, stream>>>(A, Bp, b_l, whp, bhc,
                                                elist, cursor, bsums, deg, out);
}